// Round 1
// 749.196 us; speedup vs baseline: 1.0662x; 1.0662x over previous
//
#include <hip/hip_runtime.h>

#define B_ 256
#define C_ 64
#define M_ 4096
#define S_ 4                 // M-splits for gram/apply kernels
#define GSTRIDE 4160         // 4096 gram + 64 mean-partials per (b,s)

// ============================================================================
// K1: partial Gram + mean over a 1024-wide M slice. grid (B, S_), 256 thr.
// 4 blocks/CU (LDS 39.2KB), 16 waves/CU. Cross-wave reduce in 2 rounds with
// 2 LDS buffers so LDS stays under 40KB.
// ============================================================================
__global__ __launch_bounds__(256, 4) void k_gram(const float* __restrict__ x,
                                                 float* __restrict__ wsA) {
    const int b = blockIdx.x;
    const int s = blockIdx.y;
    const int t = threadIdx.x;
    const int w = t >> 6;   // wave 0..3
    const int l = t & 63;   // lane

    __shared__ float St[64][68];   // x staging / reduce buffer
    __shared__ float Bu[64][68];   // reduce buffer
    __shared__ float ms[64][17];   // mean partials

    const float* xb = x + (size_t)b * (C_ * M_);
    float* g = wsA + (size_t)(b * S_ + s) * GSTRIDE;

    const int tc = l >> 3, td = l & 7;   // 8x8 tile coords
    const int cl = l >> 2;               // staging channel sub-index 0..15
    const int m4 = l & 3;                // staging m sub-index 0..3

    float acc[8][8];
#pragma unroll
    for (int i = 0; i < 8; ++i)
#pragma unroll
        for (int j = 0; j < 8; ++j) acc[i][j] = 0.f;
    float msum[4] = {0.f, 0.f, 0.f, 0.f};

    const int mbase = s * 1024 + w * 256;
    float4 r[4];
#pragma unroll
    for (int k = 0; k < 4; ++k)
        r[k] = *(const float4*)(xb + (size_t)(cl + 16 * k) * M_ + mbase + m4 * 4);

    for (int st = 0; st < 16; ++st) {
        __syncthreads();  // previous stage's readers done
#pragma unroll
        for (int k = 0; k < 4; ++k) {
            float4 v = r[k];
            msum[k] += v.x + v.y + v.z + v.w;
            const int row = w * 16 + m4 * 4;
            const int c = cl + 16 * k;
            St[row + 0][c] = v.x;
            St[row + 1][c] = v.y;
            St[row + 2][c] = v.z;
            St[row + 3][c] = v.w;
        }
        if (st < 15) {
#pragma unroll
            for (int k = 0; k < 4; ++k)
                r[k] = *(const float4*)(xb + (size_t)(cl + 16 * k) * M_ +
                                        mbase + (st + 1) * 16 + m4 * 4);
        }
        __syncthreads();  // stage visible
#pragma unroll 2
        for (int m = 0; m < 16; ++m) {
            float a[8], bb[8];
            *(float4*)&a[0]  = *(const float4*)&St[w * 16 + m][tc * 8];
            *(float4*)&a[4]  = *(const float4*)&St[w * 16 + m][tc * 8 + 4];
            *(float4*)&bb[0] = *(const float4*)&St[w * 16 + m][td * 8];
            *(float4*)&bb[4] = *(const float4*)&St[w * 16 + m][td * 8 + 4];
#pragma unroll
            for (int i = 0; i < 8; ++i)
#pragma unroll
                for (int j = 0; j < 8; ++j)
                    acc[i][j] = fmaf(a[i], bb[j], acc[i][j]);
        }
    }
#pragma unroll
    for (int k = 0; k < 4; ++k) ms[cl + 16 * k][w * 4 + m4] = msum[k];
    __syncthreads();

    // ---- cross-wave reduce, 2 buffers, 2 rounds ----
    if (w == 1) {
#pragma unroll
        for (int i = 0; i < 8; ++i) {
            *(float4*)&St[tc * 8 + i][td * 8]     = make_float4(acc[i][0], acc[i][1], acc[i][2], acc[i][3]);
            *(float4*)&St[tc * 8 + i][td * 8 + 4] = make_float4(acc[i][4], acc[i][5], acc[i][6], acc[i][7]);
        }
    } else if (w == 3) {
#pragma unroll
        for (int i = 0; i < 8; ++i) {
            *(float4*)&Bu[tc * 8 + i][td * 8]     = make_float4(acc[i][0], acc[i][1], acc[i][2], acc[i][3]);
            *(float4*)&Bu[tc * 8 + i][td * 8 + 4] = make_float4(acc[i][4], acc[i][5], acc[i][6], acc[i][7]);
        }
    }
    __syncthreads();
    if (w == 0) {
#pragma unroll
        for (int i = 0; i < 8; ++i) {
            float4 p = *(const float4*)&St[tc * 8 + i][td * 8];
            float4 q = *(const float4*)&St[tc * 8 + i][td * 8 + 4];
            acc[i][0] += p.x; acc[i][1] += p.y; acc[i][2] += p.z; acc[i][3] += p.w;
            acc[i][4] += q.x; acc[i][5] += q.y; acc[i][6] += q.z; acc[i][7] += q.w;
        }
    } else if (w == 2) {
#pragma unroll
        for (int i = 0; i < 8; ++i) {
            float4 p = *(const float4*)&Bu[tc * 8 + i][td * 8];
            float4 q = *(const float4*)&Bu[tc * 8 + i][td * 8 + 4];
            acc[i][0] += p.x; acc[i][1] += p.y; acc[i][2] += p.z; acc[i][3] += p.w;
            acc[i][4] += q.x; acc[i][5] += q.y; acc[i][6] += q.z; acc[i][7] += q.w;
        }
    }
    __syncthreads();
    if (w == 2) {
#pragma unroll
        for (int i = 0; i < 8; ++i) {
            *(float4*)&St[tc * 8 + i][td * 8]     = make_float4(acc[i][0], acc[i][1], acc[i][2], acc[i][3]);
            *(float4*)&St[tc * 8 + i][td * 8 + 4] = make_float4(acc[i][4], acc[i][5], acc[i][6], acc[i][7]);
        }
    }
    __syncthreads();
    if (w == 0) {
#pragma unroll
        for (int i = 0; i < 8; ++i) {
            float4 p = *(const float4*)&St[tc * 8 + i][td * 8];
            float4 q = *(const float4*)&St[tc * 8 + i][td * 8 + 4];
            float4 lo = make_float4(acc[i][0] + p.x, acc[i][1] + p.y,
                                    acc[i][2] + p.z, acc[i][3] + p.w);
            float4 hi = make_float4(acc[i][4] + q.x, acc[i][5] + q.y,
                                    acc[i][6] + q.z, acc[i][7] + q.w);
            *(float4*)(g + (size_t)(tc * 8 + i) * 64 + td * 8)     = lo;
            *(float4*)(g + (size_t)(tc * 8 + i) * 64 + td * 8 + 4) = hi;
        }
    } else if (w == 1) {
        float sum = 0.f;
#pragma unroll
        for (int q = 0; q < 16; ++q) sum += ms[l][q];
        g[4096 + l] = sum;
    }
}

// ============================================================================
// K2: reduce partials -> cov -> shrinkage -> UL Cholesky -> W = U^-1 ->
//     write W^T (with zeros) + wmu. grid B, 256 thr.
// ============================================================================
__global__ __launch_bounds__(256) void k_chol(const float* __restrict__ wsA,
                                              float* __restrict__ wsB) {
    const int b = blockIdx.x;
    const int t = threadIdx.x;

    __shared__ float Cw[64][68];
    __shared__ float Ww[64][68];
    __shared__ float mu[64];
    __shared__ float red[256];
    __shared__ float ucol[64];
    __shared__ float sc[4];

    const float* pa = wsA + (size_t)b * S_ * GSTRIDE;
    float* o = wsB + (size_t)b * GSTRIDE;

    // reduce 4 partial Grams + means
    for (int idx = t; idx < 4096; idx += 256) {
        float v = 0.f;
#pragma unroll
        for (int s = 0; s < S_; ++s) v += pa[(size_t)s * GSTRIDE + idx];
        Cw[idx >> 6][idx & 63] = v;
    }
    if (t < 64) {
        float v = 0.f;
#pragma unroll
        for (int s = 0; s < S_; ++s) v += pa[(size_t)s * GSTRIDE + 4096 + t];
        mu[t] = v * (1.0f / M_);
    }
    __syncthreads();
    // cov = G/M - mu mu^T
    for (int idx = t; idx < 4096; idx += 256) {
        int i = idx >> 6, j = idx & 63;
        Cw[i][j] = Cw[i][j] * (1.0f / M_) - mu[i] * mu[j];
    }
    __syncthreads();

    // ---- shrinkage ----
    {
        float trp = 0.f, stp = 0.f;
        for (int idx = t; idx < 4096; idx += 256) {
            int i = idx >> 6, j = idx & 63;
            float v = Cw[i][j];
            stp = fmaf(v, Cw[j][i], stp);
            if (i == j) trp += v;
        }
        red[t] = stp;
        __syncthreads();
        for (int off = 128; off > 0; off >>= 1) {
            if (t < off) red[t] += red[t + off];
            __syncthreads();
        }
        if (t == 0) sc[1] = red[0];
        __syncthreads();
        red[t] = trp;
        __syncthreads();
        for (int off = 128; off > 0; off >>= 1) {
            if (t < off) red[t] += red[t + off];
            __syncthreads();
        }
        if (t == 0) {
            float tr = red[0], st = sc[1];
            const float n = (float)M_, p = 64.f;
            float num = (n - 2.f) / n * st + tr * tr;
            float den = (n + 2.f) * (st - tr * tr / p);
            float rho = fminf(num / den, 1.0f);
            sc[0] = tr;
            sc[2] = rho;
        }
        __syncthreads();
        float rho = sc[2], tr = sc[0];
        float dadd = rho * tr * (1.0f / 64.0f);
        for (int idx = t; idx < 4096; idx += 256) {
            int i = idx >> 6, j = idx & 63;
            float v = (1.f - rho) * Cw[i][j];
            if (i == j) v += dadd;
            Cw[i][j] = v;
        }
    }

    // ---- UL Cholesky: cov = U U^T (U upper) ----
    for (int k = 63; k >= 0; --k) {
        __syncthreads();
        float dkk = sqrtf(Cw[k][k]);
        float dinv = 1.0f / dkk;
        for (int i = t; i < k; i += 256) ucol[i] = Cw[i][k] * dinv;
        if (t == 0) ucol[k] = dkk;
        __syncthreads();
        const int nel = (k * (k + 1)) >> 1;
        for (int e = t; e < nel; e += 256) {
            int j = (int)((sqrtf((float)(8 * e + 1)) - 1.0f) * 0.5f);
            if (e < ((j * (j + 1)) >> 1)) --j;
            else if (e >= (((j + 1) * (j + 2)) >> 1)) ++j;
            int i = e - ((j * (j + 1)) >> 1);
            Cw[i][j] = fmaf(-ucol[i], ucol[j], Cw[i][j]);
        }
        for (int i = t; i <= k; i += 256) Cw[i][k] = ucol[i];
    }
    __syncthreads();

    // ---- W = U^-1 (upper), lane-private columns ----
    if (t < 64) {
        const int j = t;
        Ww[j][j] = 1.0f / Cw[j][j];
        for (int i = j - 1; i >= 0; --i) {
            float s0 = 0.f, s1 = 0.f;
            int lq = i + 1;
            for (; lq + 1 <= j; lq += 2) {
                s0 = fmaf(Cw[i][lq], Ww[lq][j], s0);
                s1 = fmaf(Cw[i][lq + 1], Ww[lq + 1][j], s1);
            }
            if (lq <= j) s0 = fmaf(Cw[i][lq], Ww[lq][j], s0);
            Ww[i][j] = -(s0 + s1) / Cw[i][i];
        }
    }
    __syncthreads();
    // wmu[c] = sum_d W[c][d] mu[d]; write W^T + wmu to workspace
    if (t < 64) {
        float s = 0.f;
        for (int d = t; d < 64; ++d) s = fmaf(Ww[t][d], mu[d], s);
        o[4096 + t] = s;
    }
    for (int idx = t; idx < 4096; idx += 256) {
        int d = idx >> 6, c = idx & 63;
        o[idx] = (d >= c) ? Ww[c][d] : 0.f;
    }
}

// ============================================================================
// K3: Z = W^T x - wmu over a 1024-wide M slice. grid (B, S_), 256 thr.
// 4c x 4m register tiles; 2x ds_read_b128 per 16 FMA; float4 stores.
// LDS 35KB -> 4 blocks/CU.
// ============================================================================
__global__ __launch_bounds__(256, 4) void k_apply(const float* __restrict__ x,
                                                  const float* __restrict__ wsB,
                                                  float* __restrict__ out) {
    const int b = blockIdx.x;
    const int s = blockIdx.y;
    const int t = threadIdx.x;
    const int w = t >> 6;

    __shared__ float Wt[64][68];   // W^T: Wt[d][c]
    __shared__ float St[64][68];   // x chunk: St[d][m]
    __shared__ float wmu[64];

    const float* xb = x + (size_t)b * (C_ * M_);
    float* ob = out + (size_t)b * (C_ * M_);
    const float* wsb = wsB + (size_t)b * GSTRIDE;

    for (int idx = t; idx < 4096; idx += 256) Wt[idx >> 6][idx & 63] = wsb[idx];
    if (t < 64) wmu[t] = wsb[4096 + t];

    const int tc5 = t >> 4;   // 0..15: c-group of 4
    const int tm5 = t & 15;   // 0..15: m-group of 4
    const int cld = t >> 4;   // staging channel sub 0..15
    const int m45 = t & 15;   // staging m sub 0..15
    const int d0 = w * 16;    // wave-uniform triangular skip
    const int mbase = s * 1024;

    float4 r2[4];
#pragma unroll
    for (int k = 0; k < 4; ++k)
        r2[k] = *(const float4*)(xb + (size_t)(cld + 16 * k) * M_ + mbase + m45 * 4);

    for (int ch = 0; ch < 16; ++ch) {
        const int m0 = mbase + ch * 64;
        __syncthreads();  // first iter: covers Wt/wmu loads; later: prev readers done
#pragma unroll
        for (int k = 0; k < 4; ++k)
            *(float4*)&St[cld + 16 * k][m45 * 4] = r2[k];
        if (ch < 15) {
#pragma unroll
            for (int k = 0; k < 4; ++k)
                r2[k] = *(const float4*)(xb + (size_t)(cld + 16 * k) * M_ +
                                         m0 + 64 + m45 * 4);
        }
        __syncthreads();
        float a2[4][4];
#pragma unroll
        for (int i = 0; i < 4; ++i)
#pragma unroll
            for (int j = 0; j < 4; ++j) a2[i][j] = 0.f;
#pragma unroll 2
        for (int d = d0; d < 64; ++d) {
            float4 a  = *(const float4*)&Wt[d][tc5 * 4];
            float4 bv = *(const float4*)&St[d][tm5 * 4];
            a2[0][0] = fmaf(a.x, bv.x, a2[0][0]);
            a2[0][1] = fmaf(a.x, bv.y, a2[0][1]);
            a2[0][2] = fmaf(a.x, bv.z, a2[0][2]);
            a2[0][3] = fmaf(a.x, bv.w, a2[0][3]);
            a2[1][0] = fmaf(a.y, bv.x, a2[1][0]);
            a2[1][1] = fmaf(a.y, bv.y, a2[1][1]);
            a2[1][2] = fmaf(a.y, bv.z, a2[1][2]);
            a2[1][3] = fmaf(a.y, bv.w, a2[1][3]);
            a2[2][0] = fmaf(a.z, bv.x, a2[2][0]);
            a2[2][1] = fmaf(a.z, bv.y, a2[2][1]);
            a2[2][2] = fmaf(a.z, bv.z, a2[2][2]);
            a2[2][3] = fmaf(a.z, bv.w, a2[2][3]);
            a2[3][0] = fmaf(a.w, bv.x, a2[3][0]);
            a2[3][1] = fmaf(a.w, bv.y, a2[3][1]);
            a2[3][2] = fmaf(a.w, bv.z, a2[3][2]);
            a2[3][3] = fmaf(a.w, bv.w, a2[3][3]);
        }
#pragma unroll
        for (int i = 0; i < 4; ++i) {
            const int c = tc5 * 4 + i;
            float wv = wmu[c];
            float4 o = make_float4(a2[i][0] - wv, a2[i][1] - wv,
                                   a2[i][2] - wv, a2[i][3] - wv);
            *(float4*)(ob + (size_t)c * M_ + m0 + tm5 * 4) = o;
        }
    }
}

// ============================================================================
// Fallback: original fused single-block-per-batch kernel (used if workspace
// is too small for the 3-kernel pipeline).
// ============================================================================
__global__ __launch_bounds__(256) void k_fused(const float* __restrict__ x,
                                               float* __restrict__ out) {
    const int b = blockIdx.x;
    const int t = threadIdx.x;
    const int w = t >> 6;
    const int l = t & 63;

    __shared__ float St[64][68];
    __shared__ float Cw[64][68];
    __shared__ float Ww[64][68];
    __shared__ float ms[64][17];
    __shared__ float mu[64];
    __shared__ float red[256];
    __shared__ float ucol[64];
    __shared__ float wmu[64];
    __shared__ float sc[4];

    const float* xb = x + (size_t)b * (C_ * M_);
    float* ob = out + (size_t)b * (C_ * M_);

    const int tc = l >> 3, td = l & 7;
    const int cl = l >> 2;
    const int m4 = l & 3;

    float acc[8][8];
#pragma unroll
    for (int i = 0; i < 8; ++i)
#pragma unroll
        for (int j = 0; j < 8; ++j) acc[i][j] = 0.f;
    float msum[4] = {0.f, 0.f, 0.f, 0.f};

    const int mbase = w * 1024;
    float4 r[4];
#pragma unroll
    for (int k = 0; k < 4; ++k)
        r[k] = *(const float4*)(xb + (size_t)(cl + 16 * k) * M_ + mbase + m4 * 4);

    for (int s = 0; s < 64; ++s) {
        __syncthreads();
#pragma unroll
        for (int k = 0; k < 4; ++k) {
            float4 v = r[k];
            msum[k] += v.x + v.y + v.z + v.w;
            const int row = w * 16 + m4 * 4;
            const int c = cl + 16 * k;
            St[row + 0][c] = v.x;
            St[row + 1][c] = v.y;
            St[row + 2][c] = v.z;
            St[row + 3][c] = v.w;
        }
        if (s < 63) {
#pragma unroll
            for (int k = 0; k < 4; ++k)
                r[k] = *(const float4*)(xb + (size_t)(cl + 16 * k) * M_ +
                                        mbase + (s + 1) * 16 + m4 * 4);
        }
        __syncthreads();
#pragma unroll 2
        for (int m = 0; m < 16; ++m) {
            float a[8], bb[8];
            *(float4*)&a[0]  = *(const float4*)&St[w * 16 + m][tc * 8];
            *(float4*)&a[4]  = *(const float4*)&St[w * 16 + m][tc * 8 + 4];
            *(float4*)&bb[0] = *(const float4*)&St[w * 16 + m][td * 8];
            *(float4*)&bb[4] = *(const float4*)&St[w * 16 + m][td * 8 + 4];
#pragma unroll
            for (int i = 0; i < 8; ++i)
#pragma unroll
                for (int j = 0; j < 8; ++j)
                    acc[i][j] = fmaf(a[i], bb[j], acc[i][j]);
        }
    }
#pragma unroll
    for (int k = 0; k < 4; ++k) ms[cl + 16 * k][w * 4 + m4] = msum[k];
    __syncthreads();

    if (w == 1) {
#pragma unroll
        for (int i = 0; i < 8; ++i) {
            *(float4*)&Ww[tc * 8 + i][td * 8]     = make_float4(acc[i][0], acc[i][1], acc[i][2], acc[i][3]);
            *(float4*)&Ww[tc * 8 + i][td * 8 + 4] = make_float4(acc[i][4], acc[i][5], acc[i][6], acc[i][7]);
        }
        float s = 0.f;
#pragma unroll
        for (int q = 0; q < 16; ++q) s += ms[l][q];
        mu[l] = s * (1.0f / M_);
    } else if (w == 2) {
#pragma unroll
        for (int i = 0; i < 8; ++i) {
            *(float4*)&Cw[tc * 8 + i][td * 8]     = make_float4(acc[i][0], acc[i][1], acc[i][2], acc[i][3]);
            *(float4*)&Cw[tc * 8 + i][td * 8 + 4] = make_float4(acc[i][4], acc[i][5], acc[i][6], acc[i][7]);
        }
    } else if (w == 3) {
#pragma unroll
        for (int i = 0; i < 8; ++i) {
            *(float4*)&St[tc * 8 + i][td * 8]     = make_float4(acc[i][0], acc[i][1], acc[i][2], acc[i][3]);
            *(float4*)&St[tc * 8 + i][td * 8 + 4] = make_float4(acc[i][4], acc[i][5], acc[i][6], acc[i][7]);
        }
    }
    __syncthreads();
    if (w == 0) {
#pragma unroll
        for (int i = 0; i < 8; ++i) {
            float4 p0 = *(const float4*)&Ww[tc * 8 + i][td * 8];
            float4 p1 = *(const float4*)&Cw[tc * 8 + i][td * 8];
            float4 p2 = *(const float4*)&St[tc * 8 + i][td * 8];
            float4 q0 = *(const float4*)&Ww[tc * 8 + i][td * 8 + 4];
            float4 q1 = *(const float4*)&Cw[tc * 8 + i][td * 8 + 4];
            float4 q2 = *(const float4*)&St[tc * 8 + i][td * 8 + 4];
            float4 lo = make_float4(acc[i][0] + p0.x + p1.x + p2.x,
                                    acc[i][1] + p0.y + p1.y + p2.y,
                                    acc[i][2] + p0.z + p1.z + p2.z,
                                    acc[i][3] + p0.w + p1.w + p2.w);
            float4 hi = make_float4(acc[i][4] + q0.x + q1.x + q2.x,
                                    acc[i][5] + q0.y + q1.y + q2.y,
                                    acc[i][6] + q0.z + q1.z + q2.z,
                                    acc[i][7] + q0.w + q1.w + q2.w);
            *(float4*)&Cw[tc * 8 + i][td * 8]     = lo;
            *(float4*)&Cw[tc * 8 + i][td * 8 + 4] = hi;
        }
    }
    __syncthreads();
    for (int idx = t; idx < 4096; idx += 256) {
        int i = idx >> 6, j = idx & 63;
        Cw[i][j] = Cw[i][j] * (1.0f / M_) - mu[i] * mu[j];
    }
    __syncthreads();

    {
        float trp = 0.f, stp = 0.f;
        for (int idx = t; idx < 4096; idx += 256) {
            int i = idx >> 6, j = idx & 63;
            float v = Cw[i][j];
            stp = fmaf(v, Cw[j][i], stp);
            if (i == j) trp += v;
        }
        red[t] = stp;
        __syncthreads();
        for (int off = 128; off > 0; off >>= 1) {
            if (t < off) red[t] += red[t + off];
            __syncthreads();
        }
        if (t == 0) sc[1] = red[0];
        __syncthreads();
        red[t] = trp;
        __syncthreads();
        for (int off = 128; off > 0; off >>= 1) {
            if (t < off) red[t] += red[t + off];
            __syncthreads();
        }
        if (t == 0) {
            float tr = red[0], st = sc[1];
            const float n = (float)M_, p = 64.f;
            float num = (n - 2.f) / n * st + tr * tr;
            float den = (n + 2.f) * (st - tr * tr / p);
            float rho = fminf(num / den, 1.0f);
            sc[0] = tr;
            sc[2] = rho;
        }
        __syncthreads();
        float rho = sc[2], tr = sc[0];
        float dadd = rho * tr * (1.0f / 64.0f);
        for (int idx = t; idx < 4096; idx += 256) {
            int i = idx >> 6, j = idx & 63;
            float v = (1.f - rho) * Cw[i][j];
            if (i == j) v += dadd;
            Cw[i][j] = v;
        }
    }

    for (int k = 63; k >= 0; --k) {
        __syncthreads();
        float dkk = sqrtf(Cw[k][k]);
        float dinv = 1.0f / dkk;
        for (int i = t; i < k; i += 256) ucol[i] = Cw[i][k] * dinv;
        if (t == 0) ucol[k] = dkk;
        __syncthreads();
        const int nel = (k * (k + 1)) >> 1;
        for (int e = t; e < nel; e += 256) {
            int j = (int)((sqrtf((float)(8 * e + 1)) - 1.0f) * 0.5f);
            if (e < ((j * (j + 1)) >> 1)) --j;
            else if (e >= (((j + 1) * (j + 2)) >> 1)) ++j;
            int i = e - ((j * (j + 1)) >> 1);
            Cw[i][j] = fmaf(-ucol[i], ucol[j], Cw[i][j]);
        }
        for (int i = t; i <= k; i += 256) Cw[i][k] = ucol[i];
    }
    __syncthreads();

    if (t < 64) {
        const int j = t;
        Ww[j][j] = 1.0f / Cw[j][j];
        for (int i = j - 1; i >= 0; --i) {
            float s0 = 0.f, s1 = 0.f;
            int lq = i + 1;
            for (; lq + 1 <= j; lq += 2) {
                s0 = fmaf(Cw[i][lq], Ww[lq][j], s0);
                s1 = fmaf(Cw[i][lq + 1], Ww[lq + 1][j], s1);
            }
            if (lq <= j) s0 = fmaf(Cw[i][lq], Ww[lq][j], s0);
            Ww[i][j] = -(s0 + s1) / Cw[i][i];
        }
    }
    __syncthreads();
    if (t < 64) {
        float s = 0.f;
        for (int d = t; d < 64; ++d) s = fmaf(Ww[t][d], mu[d], s);
        wmu[t] = s;
    }
    for (int idx = t; idx < 4096; idx += 256) {
        int d = idx >> 6, c = idx & 63;
        Cw[d][c] = (d >= c) ? Ww[c][d] : 0.f;
    }

    const int tc5 = t >> 5;
    const int tm5 = t & 31;
    const int cld = t >> 4;
    const int m45 = t & 15;
    const int d0 = w * 16;

    float4 r2[4];
#pragma unroll
    for (int k = 0; k < 4; ++k)
        r2[k] = *(const float4*)(xb + (size_t)(cld + 16 * k) * M_ + m45 * 4);

    for (int ch = 0; ch < 64; ++ch) {
        const int m0 = ch * 64;
        __syncthreads();
#pragma unroll
        for (int k = 0; k < 4; ++k)
            *(float4*)&St[cld + 16 * k][m45 * 4] = r2[k];
        if (ch < 63) {
#pragma unroll
            for (int k = 0; k < 4; ++k)
                r2[k] = *(const float4*)(xb + (size_t)(cld + 16 * k) * M_ +
                                         m0 + 64 + m45 * 4);
        }
        __syncthreads();
        float a2[8][2];
#pragma unroll
        for (int i = 0; i < 8; ++i) a2[i][0] = a2[i][1] = 0.f;
        for (int d = d0; d < 64; ++d) {
            float a[8];
            *(float4*)&a[0] = *(const float4*)&Cw[d][tc5 * 8];
            *(float4*)&a[4] = *(const float4*)&Cw[d][tc5 * 8 + 4];
            float2 bv = *(const float2*)&St[d][tm5 * 2];
#pragma unroll
            for (int i = 0; i < 8; ++i) {
                a2[i][0] = fmaf(a[i], bv.x, a2[i][0]);
                a2[i][1] = fmaf(a[i], bv.y, a2[i][1]);
            }
        }
#pragma unroll
        for (int i = 0; i < 8; ++i) {
            const int c = tc5 * 8 + i;
            float wv = wmu[c];
            float2 o = make_float2(a2[i][0] - wv, a2[i][1] - wv);
            *(float2*)(ob + (size_t)c * M_ + m0 + tm5 * 2) = o;
        }
    }
}

extern "C" void kernel_launch(void* const* d_in, const int* in_sizes, int n_in,
                              void* d_out, int out_size, void* d_ws, size_t ws_size,
                              hipStream_t stream) {
    const float* x = (const float*)d_in[0];
    float* out = (float*)d_out;
    const size_t needed = (size_t)(B_ * S_ + B_) * GSTRIDE * sizeof(float);
    if (d_ws && ws_size >= needed) {
        float* wsA = (float*)d_ws;
        float* wsB = wsA + (size_t)B_ * S_ * GSTRIDE;
        k_gram<<<dim3(B_, S_), 256, 0, stream>>>(x, wsA);
        k_chol<<<dim3(B_), 256, 0, stream>>>(wsA, wsB);
        k_apply<<<dim3(B_, S_), 256, 0, stream>>>(x, wsB, out);
    } else {
        k_fused<<<dim3(B_), 256, 0, stream>>>(x, out);
    }
}